// Round 12
// baseline (861.891 us; speedup 1.0000x reference)
//
#include <hip/hip_runtime.h>
#include <hip/hip_bf16.h>

// VariationalGCNEncoder: 4x GCNConv chain on a fixed random graph.
// CSR build v5: scatter into 3125 coarse cells (32 nodes each, CAP 1280).
// Round-11 lesson: write amplification is set by line-fill time vs L2
// eviction horizon (cell count), NOT XCD mapping (XCC_ID windows left
// WRITE_SIZE at 133MB). 3125 cells -> ~45ns between appends to a cell ->
// 64B line fills in <1us -> amplification ~1. Contention: 1024 same-address
// atomics per cell, ~4-6us total. Then 3125-bin scan + per-bin (32-node)
// LDS counting sort -> csr, offs, dinv.
// Layers: MFMA GEMM (16x16x32 bf16, B-frags in regs, dinv prescale) ->
// full-row gather-aggregate (wave per node, lane = col pair, 8-deep ILP).

typedef unsigned int uint;
typedef unsigned short ushort_t;
typedef __attribute__((ext_vector_type(8))) short bf16x8;
typedef __attribute__((ext_vector_type(4))) float f32x4;

__device__ __forceinline__ float bflo(uint u) { return __uint_as_float(u << 16); }
__device__ __forceinline__ float bfhi(uint u) { return __uint_as_float(u & 0xFFFF0000u); }
__device__ __forceinline__ ushort_t f2bf(float f) {
  union { float f; uint u; } v; v.f = f;
  uint r = v.u + 0x7FFFu + ((v.u >> 16) & 1u);  // round-nearest-even
  return (ushort_t)(r >> 16);
}

#define B2SH 5      // 32 nodes per bin
#define CAP2 1280   // bin capacity; load Poisson(1024), 1280 = +8 sigma

// ---- CSR build ------------------------------------------------------------

__global__ void k_scatter(const int* __restrict__ src, const int* __restrict__ dst,
                          int E, int* __restrict__ cnt, uint* __restrict__ ebuf) {
  int i = blockIdx.x * 256 + threadIdx.x;
  if (2 * i + 1 < E) {
    int2 s2 = *(const int2*)(src + 2 * i);
    int2 d2 = *(const int2*)(dst + 2 * i);
    int c0 = d2.x >> B2SH;
    int p0 = atomicAdd(&cnt[c0], 1);
    if (p0 < CAP2) ebuf[c0 * CAP2 + p0] = (uint)s2.x | ((uint)(d2.x & 31) << 17);
    int c1 = d2.y >> B2SH;
    int p1 = atomicAdd(&cnt[c1], 1);
    if (p1 < CAP2) ebuf[c1 * CAP2 + p1] = (uint)s2.y | ((uint)(d2.y & 31) << 17);
  }
}

// Exclusive scan over NB2 (~3125) bin counts.
__global__ __launch_bounds__(1024) void k_bscan(const int* __restrict__ cnt,
                                                int* __restrict__ boffs,
                                                int NB2, int E) {
  __shared__ int sc[1024];
  const int t = threadIdx.x;
  int run = 0;
  for (int base = 0; base < NB2; base += 1024) {
    int i = base + t;
    int c = (i < NB2) ? min(cnt[i], CAP2) : 0;
    sc[t] = c;
    __syncthreads();
    for (int off = 1; off < 1024; off <<= 1) {
      int u = (t >= off) ? sc[t - off] : 0;
      __syncthreads();
      sc[t] += u;
      __syncthreads();
    }
    if (i < NB2) boffs[i] = run + sc[t] - c;
    int total = sc[1023];
    __syncthreads();
    run += total;
  }
  if (t == 0) boffs[NB2] = E;
}

// Per-bin (32 nodes) LDS counting sort: emits csr, offs, dinv.
__global__ __launch_bounds__(256) void k_binfill(const int* __restrict__ cnt,
                                                 const int* __restrict__ boffs,
                                                 const uint* __restrict__ ebuf,
                                                 int* __restrict__ csr,
                                                 int* __restrict__ offs,
                                                 float* __restrict__ dinv,
                                                 int N, int E) {
  __shared__ uint led[CAP2];
  __shared__ int lcnt[32], lbase[32];
  const int b = blockIdx.x;
  const int t = threadIdx.x;
  const int lo = boffs[b];
  const int cntb = min(cnt[b], CAP2);
  if (t < 32) lcnt[t] = 0;
  __syncthreads();
  for (int e = t; e < cntb; e += 256) {
    uint p = ebuf[b * CAP2 + e];
    led[e] = p;
    atomicAdd(&lcnt[(p >> 17) & 31], 1);
  }
  __syncthreads();
  if (t == 0) {
    int run = lo;
#pragma unroll
    for (int k = 0; k < 32; k++) { lbase[k] = run; run += lcnt[k]; }
  }
  __syncthreads();
  if (t < 32) {
    int node = (b << B2SH) + t;
    if (node < N) {
      offs[node] = lbase[t];
      dinv[node] = rsqrtf((float)(lcnt[t] + 1));
    }
  }
  if (b == 0 && t == 32) offs[N] = E;
  if (t < 32) lcnt[t] = 0;
  __syncthreads();
  for (int e = t; e < cntb; e += 256) {
    uint p = led[e];
    int k = (int)((p >> 17) & 31);
    int r = atomicAdd(&lcnt[k], 1);
    csr[lbase[k] + r] = (int)(p & 0x1FFFF);
  }
}

// ---- fp32 -> bf16 bulk convert (for x) ------------------------------------

__global__ void k_cvt(const float* __restrict__ in, uint* __restrict__ out, int n8) {
  int i = blockIdx.x * 256 + threadIdx.x;
  if (i < n8) {
    float4 a = *(const float4*)(in + 8 * i);
    float4 b = *(const float4*)(in + 8 * i + 4);
    uint4 o;
    o.x = (uint)f2bf(a.x) | ((uint)f2bf(a.y) << 16);
    o.y = (uint)f2bf(a.z) | ((uint)f2bf(a.w) << 16);
    o.z = (uint)f2bf(b.x) | ((uint)f2bf(b.y) << 16);
    o.w = (uint)f2bf(b.z) | ((uint)f2bf(b.w) << 16);
    *(uint4*)(out + 4 * i) = o;
  }
}

// ---- MFMA GEMM: H[r] = dinv[r] * (X[r] @ W), bf16 in/out ------------------

template <int CIN, int COUT>
__global__ __launch_bounds__(256) void k_mgemm(const __hip_bfloat16* __restrict__ X,
                                               const float* __restrict__ W,
                                               const float* __restrict__ dinv,
                                               __hip_bfloat16* __restrict__ H, int N) {
  constexpr int KCH = CIN / 32;
  constexpr int TPW = COUT / 64;
  const int wid = threadIdx.x >> 6, lane = threadIdx.x & 63;
  const int l16 = lane & 15, lg = lane >> 4;
  const int cb = wid * (COUT / 4);
  bf16x8 bfr[TPW][KCH];
#pragma unroll
  for (int t = 0; t < TPW; t++) {
#pragma unroll
    for (int ch = 0; ch < KCH; ch++) {
      const int col = cb + t * 16 + l16;
      const int k0 = ch * 32 + lg * 8;
#pragma unroll
      for (int j = 0; j < 8; j++)
        bfr[t][ch][j] = (short)f2bf(W[(size_t)(k0 + j) * COUT + col]);
    }
  }
  const int RB = (N + 15) >> 4;
  for (int rb = blockIdx.x; rb < RB; rb += gridDim.x) {
    const int r0 = rb << 4;
    const int arow = min(r0 + l16, N - 1);
    const __hip_bfloat16* xr = X + (size_t)arow * CIN + lg * 8;
    bf16x8 afr[KCH];
#pragma unroll
    for (int ch = 0; ch < KCH; ch++) afr[ch] = *(const bf16x8*)(xr + ch * 32);
    f32x4 acc[TPW];
#pragma unroll
    for (int t = 0; t < TPW; t++) acc[t] = (f32x4){0.f, 0.f, 0.f, 0.f};
#pragma unroll
    for (int ch = 0; ch < KCH; ch++) {
#pragma unroll
      for (int t = 0; t < TPW; t++)
        acc[t] = __builtin_amdgcn_mfma_f32_16x16x32_bf16(afr[ch], bfr[t][ch], acc[t], 0, 0, 0);
    }
#pragma unroll
    for (int r = 0; r < 4; r++) {
      const int orow = r0 + lg * 4 + r;
      if (orow < N) {
        const float dv = dinv[orow];
#pragma unroll
        for (int t = 0; t < TPW; t++)
          *(ushort_t*)(H + (size_t)orow * COUT + cb + t * 16 + l16) = f2bf(dv * acc[t][r]);
      }
    }
  }
}

// ---- Aggregation, C=128, ReLU, bf16 out (layers 1 & 3) --------------------

__global__ __launch_bounds__(256) void k_agg128(const __hip_bfloat16* __restrict__ H,
                                                const int* __restrict__ offs,
                                                const int* __restrict__ csr,
                                                const float* __restrict__ dinv,
                                                const float* __restrict__ b,
                                                __hip_bfloat16* __restrict__ OUT, int N) {
  const int lane = threadIdx.x & 63, wid = threadIdx.x >> 6;
  const int i = blockIdx.x * 4 + wid;
  if (i >= N) return;
  const int c = lane * 2;
  const float b0 = b[c], b1 = b[c + 1];
  const int beg = offs[i], end = offs[i + 1];
  float a0 = 0, a1 = 0;
  int e = beg;
  for (; e + 8 <= end; e += 8) {
    int s0 = csr[e], s1 = csr[e + 1], s2 = csr[e + 2], s3 = csr[e + 3];
    int s4 = csr[e + 4], s5 = csr[e + 5], s6 = csr[e + 6], s7 = csr[e + 7];
    uint h0 = *(const uint*)(H + (size_t)s0 * 128 + c);
    uint h1 = *(const uint*)(H + (size_t)s1 * 128 + c);
    uint h2 = *(const uint*)(H + (size_t)s2 * 128 + c);
    uint h3 = *(const uint*)(H + (size_t)s3 * 128 + c);
    uint h4 = *(const uint*)(H + (size_t)s4 * 128 + c);
    uint h5 = *(const uint*)(H + (size_t)s5 * 128 + c);
    uint h6 = *(const uint*)(H + (size_t)s6 * 128 + c);
    uint h7 = *(const uint*)(H + (size_t)s7 * 128 + c);
    a0 += bflo(h0) + bflo(h1) + bflo(h2) + bflo(h3);
    a1 += bfhi(h0) + bfhi(h1) + bfhi(h2) + bfhi(h3);
    a0 += bflo(h4) + bflo(h5) + bflo(h6) + bflo(h7);
    a1 += bfhi(h4) + bfhi(h5) + bfhi(h6) + bfhi(h7);
  }
  if (e + 4 <= end) {
    int s0 = csr[e], s1 = csr[e + 1], s2 = csr[e + 2], s3 = csr[e + 3];
    uint h0 = *(const uint*)(H + (size_t)s0 * 128 + c);
    uint h1 = *(const uint*)(H + (size_t)s1 * 128 + c);
    uint h2 = *(const uint*)(H + (size_t)s2 * 128 + c);
    uint h3 = *(const uint*)(H + (size_t)s3 * 128 + c);
    a0 += bflo(h0) + bflo(h1) + bflo(h2) + bflo(h3);
    a1 += bfhi(h0) + bfhi(h1) + bfhi(h2) + bfhi(h3);
    e += 4;
  }
  for (; e < end; e++) {
    int s = csr[e];
    uint h = *(const uint*)(H + (size_t)s * 128 + c);
    a0 += bflo(h);
    a1 += bfhi(h);
  }
  const float di = dinv[i];
  uint hs = *(const uint*)(H + (size_t)i * 128 + c);
  float r0 = di * (a0 + bflo(hs)) + b0;
  float r1 = di * (a1 + bfhi(hs)) + b1;
  r0 = fmaxf(r0, 0.f);
  r1 = fmaxf(r1, 0.f);
  *(uint*)(OUT + (size_t)i * 128 + c) = (uint)f2bf(r0) | ((uint)f2bf(r1) << 16);
}

// ---- Aggregation, C=64, no ReLU, fp32 out (+optional bf16 mirror) ---------

__global__ __launch_bounds__(256) void k_agg64(const __hip_bfloat16* __restrict__ H,
                                               const int* __restrict__ offs,
                                               const int* __restrict__ csr,
                                               const float* __restrict__ dinv,
                                               const float* __restrict__ b,
                                               float* __restrict__ OUT,
                                               __hip_bfloat16* __restrict__ MIR, int N) {
  const int lane = threadIdx.x & 63, wid = threadIdx.x >> 6;
  const int i = blockIdx.x * 4 + wid;
  if (i >= N) return;
  const int half = lane >> 5;
  const int c = (lane & 31) * 2;
  const float b0 = b[c], b1 = b[c + 1];
  const int beg = offs[i], end = offs[i + 1];
  float a0 = 0, a1 = 0;
  int e = beg + half;
  for (; e + 6 < end; e += 8) {
    int s0 = csr[e], s1 = csr[e + 2], s2 = csr[e + 4], s3 = csr[e + 6];
    uint h0 = *(const uint*)(H + (size_t)s0 * 64 + c);
    uint h1 = *(const uint*)(H + (size_t)s1 * 64 + c);
    uint h2 = *(const uint*)(H + (size_t)s2 * 64 + c);
    uint h3 = *(const uint*)(H + (size_t)s3 * 64 + c);
    a0 += bflo(h0) + bflo(h1) + bflo(h2) + bflo(h3);
    a1 += bfhi(h0) + bfhi(h1) + bfhi(h2) + bfhi(h3);
  }
  for (; e < end; e += 2) {
    int s = csr[e];
    uint h = *(const uint*)(H + (size_t)s * 64 + c);
    a0 += bflo(h);
    a1 += bfhi(h);
  }
  a0 += __shfl_xor(a0, 32);
  a1 += __shfl_xor(a1, 32);
  const float di = dinv[i];
  uint hs = *(const uint*)(H + (size_t)i * 64 + c);
  float r0 = di * (a0 + bflo(hs)) + b0;
  float r1 = di * (a1 + bfhi(hs)) + b1;
  if (lane < 32) {
    *(float2*)(OUT + (size_t)i * 64 + c) = make_float2(r0, r1);
    if (MIR) *(uint*)(MIR + (size_t)i * 64 + c) = (uint)f2bf(r0) | ((uint)f2bf(r1) << 16);
  }
}

// ---- Launch ---------------------------------------------------------------

extern "C" void kernel_launch(void* const* d_in, const int* in_sizes, int n_in,
                              void* d_out, int out_size, void* d_ws, size_t ws_size,
                              hipStream_t stream) {
  const float* x   = (const float*)d_in[0];
  const int*   ei  = (const int*)d_in[1];
  const float* W1n = (const float*)d_in[2];
  const float* b1n = (const float*)d_in[3];
  const float* W2n = (const float*)d_in[4];
  const float* b2n = (const float*)d_in[5];
  const float* W1e = (const float*)d_in[6];
  const float* b1e = (const float*)d_in[7];
  const float* W2e = (const float*)d_in[8];
  const float* b2e = (const float*)d_in[9];
  float* out = (float*)d_out;

  const int N = in_sizes[0] / 128;   // 100000
  const int E = in_sizes[1] / 2;     // 3200000
  const int NB2 = (N + 31) >> B2SH;  // 32-node bins (3125)
  const int* src = ei;
  const int* dst = ei + E;

  // workspace carve (256B aligned regions)
  char* p = (char*)d_ws;
  auto alloc = [&](size_t bytes) {
    void* q = (void*)p;
    p += (bytes + 255) & ~(size_t)255;
    return q;
  };
  int*   cnt   = (int*)alloc((size_t)NB2 * 4);
  int*   boffs = (int*)alloc((size_t)(NB2 + 1) * 4);
  int*   offs  = (int*)alloc((size_t)(N + 1) * 4);
  float* dinv  = (float*)alloc((size_t)N * 4);
  int*   csr   = (int*)alloc((size_t)E * 4);
  __hip_bfloat16* hbuf = (__hip_bfloat16*)alloc((size_t)N * 128 * 2);
  __hip_bfloat16* abuf = (__hip_bfloat16*)alloc((size_t)N * 128 * 2);
  uint* ebuf = (uint*)hbuf;  // CSR staging aliases hbuf: NB2*CAP2*4 = 16MB <= 25.6MB

  const int RB = (N + 15) >> 4;
  const int GEMM_GRID = RB < 1024 ? RB : 1024;

  // graph structure (shared by all 4 layers)
  hipMemsetAsync(cnt, 0, (size_t)NB2 * 4, stream);
  k_scatter<<<(E / 2 + 255) / 256, 256, 0, stream>>>(src, dst, E, cnt, ebuf);
  k_bscan<<<1, 1024, 0, stream>>>(cnt, boffs, NB2, E);
  k_binfill<<<NB2, 256, 0, stream>>>(cnt, boffs, ebuf, csr, offs, dinv, N, E);

  // x -> bf16 (abuf)
  k_cvt<<<(N * 128 / 8 + 255) / 256, 256, 0, stream>>>(x, (uint*)abuf, N * 128 / 8);

  // layer 1
  k_mgemm<128, 128><<<GEMM_GRID, 256, 0, stream>>>(abuf, W1n, dinv, hbuf, N);
  k_agg128<<<(N + 3) / 4, 256, 0, stream>>>(hbuf, offs, csr, dinv, b1n, abuf, N);

  // layer 2: mu -> d_out[0:N*64), bf16 mirror -> abuf
  k_mgemm<128, 64><<<GEMM_GRID, 256, 0, stream>>>(abuf, W2n, dinv, hbuf, N);
  k_agg64<<<(N + 3) / 4, 256, 0, stream>>>(hbuf, offs, csr, dinv, b2n, out, abuf, N);

  // layer 3
  k_mgemm<64, 128><<<GEMM_GRID, 256, 0, stream>>>(abuf, W1e, dinv, hbuf, N);
  k_agg128<<<(N + 3) / 4, 256, 0, stream>>>(hbuf, offs, csr, dinv, b1e, abuf, N);

  // layer 4: logstd -> d_out[N*64 : 2*N*64)
  k_mgemm<128, 64><<<GEMM_GRID, 256, 0, stream>>>(abuf, W2e, dinv, hbuf, N);
  k_agg64<<<(N + 3) / 4, 256, 0, stream>>>(hbuf, offs, csr, dinv, b2e, out + (size_t)N * 64,
                                           (__hip_bfloat16*)nullptr, N);
}

// Round 14
// 645.708 us; speedup vs baseline: 1.3348x; 1.3348x over previous
//
#include <hip/hip_runtime.h>
#include <hip/hip_bf16.h>

// VariationalGCNEncoder: 4x GCNConv chain on a fixed random graph.
// CSR build v6 (atomic-free): rounds 9-12 falsified XCD-mapping and
// cell-count theories; the invariant ~130-160MB WRITE_SIZE tracks the E
// global atomicAdds (memory-side RMW on the 8-XCD part). v6 has ZERO global
// atomics: per-partition LDS counting sort (k_part, coalesced writes) ->
// transpose (k_tr) -> cell totals + scan (k_ctot/k_bscan) -> per-cell run
// merge + 32-node LDS counting sort (k_binfill2) -> csr, offs, dinv.
// Layers: MFMA GEMM (16x16x32 bf16, B-frags in regs, dinv prescale) ->
// full-row gather-aggregate (wave per node, lane = col pair, 8-deep ILP).

typedef unsigned int uint;
typedef unsigned short ushort_t;
typedef __attribute__((ext_vector_type(8))) short bf16x8;
typedef __attribute__((ext_vector_type(4))) float f32x4;

__device__ __forceinline__ float bflo(uint u) { return __uint_as_float(u << 16); }
__device__ __forceinline__ float bfhi(uint u) { return __uint_as_float(u & 0xFFFF0000u); }
__device__ __forceinline__ ushort_t f2bf(float f) {
  union { float f; uint u; } v; v.f = f;
  uint r = v.u + 0x7FFFu + ((v.u >> 16) & 1u);  // round-nearest-even
  return (ushort_t)(r >> 16);
}

#define EPB 8192    // edges per partition
#define CMAX 3136   // LDS histogram slots (>= C = ceil(N/32) = 3125)
#define LEDCAP 1536 // per-cell LDS edge cap; cell load Poisson(1024), +16 sigma

// ---- CSR build (no global atomics) ----------------------------------------

// Partition-local counting sort by 32-node cell. All contention in LDS;
// all global writes coalesced (psorted run + hist/pstart rows).
__global__ __launch_bounds__(256) void k_part(const int* __restrict__ src,
                                              const int* __restrict__ dst,
                                              int E, int C,
                                              uint* __restrict__ psorted,
                                              int* __restrict__ hist,
                                              int* __restrict__ pstart) {
  __shared__ uint led[EPB];
  __shared__ int lhist[CMAX], lcur[CMAX], part[256];
  const int p = blockIdx.x, t = threadIdx.x;
  const int e0 = p * EPB;
  const int cntp = min(EPB, E - e0);
  for (int i = t; i < C; i += 256) lhist[i] = 0;
  __syncthreads();
  for (int j = t; j < cntp; j += 256) atomicAdd(&lhist[dst[e0 + j] >> 5], 1);
  __syncthreads();
  // exclusive scan of lhist -> lcur (chunk-of-13 per thread + block scan)
  const int lo = t * 13, hi = min(lo + 13, C);
  int s = 0;
  for (int i = lo; i < hi; i++) s += lhist[i];
  part[t] = s;
  __syncthreads();
  for (int o = 1; o < 256; o <<= 1) {
    int u = (t >= o) ? part[t - o] : 0;
    __syncthreads();
    part[t] += u;
    __syncthreads();
  }
  int run = part[t] - s;
  for (int i = lo; i < hi; i++) { lcur[i] = run; run += lhist[i]; }
  __syncthreads();
  // scatter edges into LDS in cell order
  for (int j = t; j < cntp; j += 256) {
    int sv = src[e0 + j], d = dst[e0 + j];
    int pos = atomicAdd(&lcur[d >> 5], 1);
    led[pos] = (uint)sv | ((uint)(d & 31) << 17);
  }
  __syncthreads();
  for (int j = t; j < cntp; j += 256) psorted[e0 + j] = led[j];
  for (int i = t; i < C; i += 256) {
    int h = lhist[i];
    hist[(size_t)p * C + i] = h;
    pstart[(size_t)p * C + i] = lcur[i] - h;
  }
}

// Transpose hist & pstart [P][C] -> [C][P] (32x32 LDS tiles, both coalesced).
__global__ __launch_bounds__(256) void k_tr(const int* __restrict__ A, int* __restrict__ AT,
                                            const int* __restrict__ Bm, int* __restrict__ BT,
                                            int P, int C) {
  __shared__ int ta[32][33], tb[32][33];
  const int pc = blockIdx.x * 32, cc = blockIdx.y * 32;
  const int tx = threadIdx.x & 31, ty = threadIdx.x >> 5;
  for (int r = ty; r < 32; r += 8) {
    int p = pc + r, c = cc + tx;
    if (p < P && c < C) {
      ta[r][tx] = A[(size_t)p * C + c];
      tb[r][tx] = Bm[(size_t)p * C + c];
    }
  }
  __syncthreads();
  for (int r = ty; r < 32; r += 8) {
    int c = cc + r, p = pc + tx;
    if (c < C && p < P) {
      AT[(size_t)c * P + p] = ta[tx][r];
      BT[(size_t)c * P + p] = tb[tx][r];
    }
  }
}

// Per-cell totals: wave per cell, coalesced row reduce.
__global__ __launch_bounds__(256) void k_ctot(const int* __restrict__ histT,
                                              int* __restrict__ ctot, int C, int P) {
  const int w = (blockIdx.x * 256 + threadIdx.x) >> 6, l = threadIdx.x & 63;
  if (w >= C) return;
  int s = 0;
  for (int p = l; p < P; p += 64) s += histT[(size_t)w * P + p];
  for (int o = 32; o; o >>= 1) s += __shfl_xor(s, o);
  if (l == 0) ctot[w] = s;
}

// Exclusive scan over C cell totals -> boffs.
__global__ __launch_bounds__(1024) void k_bscan(const int* __restrict__ ctot,
                                                int* __restrict__ boffs,
                                                int C, int E) {
  __shared__ int sc[1024];
  const int t = threadIdx.x;
  int run = 0;
  for (int base = 0; base < C; base += 1024) {
    int i = base + t;
    int c = (i < C) ? ctot[i] : 0;
    sc[t] = c;
    __syncthreads();
    for (int off = 1; off < 1024; off <<= 1) {
      int u = (t >= off) ? sc[t - off] : 0;
      __syncthreads();
      sc[t] += u;
      __syncthreads();
    }
    if (i < C) boffs[i] = run + sc[t] - c;
    int total = sc[1023];
    __syncthreads();
    run += total;
  }
  if (t == 0) boffs[C] = E;
}

// Per-cell: merge the P runs from psorted into LDS, then 32-node counting
// sort -> csr (contiguous), offs, dinv.
__global__ __launch_bounds__(256) void k_binfill2(const int* __restrict__ histT,
                                                  const int* __restrict__ pstartT,
                                                  const uint* __restrict__ psorted,
                                                  const int* __restrict__ boffs,
                                                  int* __restrict__ csr,
                                                  int* __restrict__ offs,
                                                  float* __restrict__ dinv,
                                                  int N, int E, int C, int P) {
  __shared__ uint led[LEDCAP];
  __shared__ int part[256];
  __shared__ int lcnt[32], lbase[32];
  const int c = blockIdx.x, t = threadIdx.x;
  const int v0 = (t < P) ? histT[(size_t)c * P + t] : 0;
  const int v1 = (t + 256 < P) ? histT[(size_t)c * P + t + 256] : 0;
  int s = v0 + v1;
  part[t] = s;
  __syncthreads();
  for (int o = 1; o < 256; o <<= 1) {
    int u = (t >= o) ? part[t - o] : 0;
    __syncthreads();
    part[t] += u;
    __syncthreads();
  }
  const int base = part[t] - s;   // exclusive prefix for this thread's runs
  const int cntb = part[255];     // cell total
  if (v0) {
    int sp = t * EPB + pstartT[(size_t)c * P + t];
    for (int k = 0; k < v0; k++) led[base + k] = psorted[sp + k];
  }
  if (v1) {
    int sp = (t + 256) * EPB + pstartT[(size_t)c * P + t + 256];
    for (int k = 0; k < v1; k++) led[base + v0 + k] = psorted[sp + k];
  }
  if (t < 32) lcnt[t] = 0;
  __syncthreads();
  for (int e = t; e < cntb; e += 256) atomicAdd(&lcnt[(led[e] >> 17) & 31], 1);
  __syncthreads();
  if (t == 0) {
    int run = boffs[c];
#pragma unroll
    for (int k = 0; k < 32; k++) { lbase[k] = run; run += lcnt[k]; }
  }
  __syncthreads();
  if (t < 32) {
    int node = (c << 5) + t;
    if (node < N) {
      offs[node] = lbase[t];
      dinv[node] = rsqrtf((float)(lcnt[t] + 1));
    }
  }
  if (c == 0 && t == 32) offs[N] = E;
  if (t < 32) lcnt[t] = 0;
  __syncthreads();
  for (int e = t; e < cntb; e += 256) {
    uint q = led[e];
    int k = (int)((q >> 17) & 31);
    int r = atomicAdd(&lcnt[k], 1);
    csr[lbase[k] + r] = (int)(q & 0x1FFFF);
  }
}

// ---- fp32 -> bf16 bulk convert (for x) ------------------------------------

__global__ void k_cvt(const float* __restrict__ in, uint* __restrict__ out, int n8) {
  int i = blockIdx.x * 256 + threadIdx.x;
  if (i < n8) {
    float4 a = *(const float4*)(in + 8 * i);
    float4 b = *(const float4*)(in + 8 * i + 4);
    uint4 o;
    o.x = (uint)f2bf(a.x) | ((uint)f2bf(a.y) << 16);
    o.y = (uint)f2bf(a.z) | ((uint)f2bf(a.w) << 16);
    o.z = (uint)f2bf(b.x) | ((uint)f2bf(b.y) << 16);
    o.w = (uint)f2bf(b.z) | ((uint)f2bf(b.w) << 16);
    *(uint4*)(out + 4 * i) = o;
  }
}

// ---- MFMA GEMM: H[r] = dinv[r] * (X[r] @ W), bf16 in/out ------------------

template <int CIN, int COUT>
__global__ __launch_bounds__(256) void k_mgemm(const __hip_bfloat16* __restrict__ X,
                                               const float* __restrict__ W,
                                               const float* __restrict__ dinv,
                                               __hip_bfloat16* __restrict__ H, int N) {
  constexpr int KCH = CIN / 32;
  constexpr int TPW = COUT / 64;
  const int wid = threadIdx.x >> 6, lane = threadIdx.x & 63;
  const int l16 = lane & 15, lg = lane >> 4;
  const int cb = wid * (COUT / 4);
  bf16x8 bfr[TPW][KCH];
#pragma unroll
  for (int t = 0; t < TPW; t++) {
#pragma unroll
    for (int ch = 0; ch < KCH; ch++) {
      const int col = cb + t * 16 + l16;
      const int k0 = ch * 32 + lg * 8;
#pragma unroll
      for (int j = 0; j < 8; j++)
        bfr[t][ch][j] = (short)f2bf(W[(size_t)(k0 + j) * COUT + col]);
    }
  }
  const int RB = (N + 15) >> 4;
  for (int rb = blockIdx.x; rb < RB; rb += gridDim.x) {
    const int r0 = rb << 4;
    const int arow = min(r0 + l16, N - 1);
    const __hip_bfloat16* xr = X + (size_t)arow * CIN + lg * 8;
    bf16x8 afr[KCH];
#pragma unroll
    for (int ch = 0; ch < KCH; ch++) afr[ch] = *(const bf16x8*)(xr + ch * 32);
    f32x4 acc[TPW];
#pragma unroll
    for (int t = 0; t < TPW; t++) acc[t] = (f32x4){0.f, 0.f, 0.f, 0.f};
#pragma unroll
    for (int ch = 0; ch < KCH; ch++) {
#pragma unroll
      for (int t = 0; t < TPW; t++)
        acc[t] = __builtin_amdgcn_mfma_f32_16x16x32_bf16(afr[ch], bfr[t][ch], acc[t], 0, 0, 0);
    }
#pragma unroll
    for (int r = 0; r < 4; r++) {
      const int orow = r0 + lg * 4 + r;
      if (orow < N) {
        const float dv = dinv[orow];
#pragma unroll
        for (int t = 0; t < TPW; t++)
          *(ushort_t*)(H + (size_t)orow * COUT + cb + t * 16 + l16) = f2bf(dv * acc[t][r]);
      }
    }
  }
}

// ---- Aggregation, C=128, ReLU, bf16 out (layers 1 & 3) --------------------

__global__ __launch_bounds__(256) void k_agg128(const __hip_bfloat16* __restrict__ H,
                                                const int* __restrict__ offs,
                                                const int* __restrict__ csr,
                                                const float* __restrict__ dinv,
                                                const float* __restrict__ b,
                                                __hip_bfloat16* __restrict__ OUT, int N) {
  const int lane = threadIdx.x & 63, wid = threadIdx.x >> 6;
  const int i = blockIdx.x * 4 + wid;
  if (i >= N) return;
  const int c = lane * 2;
  const float b0 = b[c], b1 = b[c + 1];
  const int beg = offs[i], end = offs[i + 1];
  float a0 = 0, a1 = 0;
  int e = beg;
  for (; e + 8 <= end; e += 8) {
    int s0 = csr[e], s1 = csr[e + 1], s2 = csr[e + 2], s3 = csr[e + 3];
    int s4 = csr[e + 4], s5 = csr[e + 5], s6 = csr[e + 6], s7 = csr[e + 7];
    uint h0 = *(const uint*)(H + (size_t)s0 * 128 + c);
    uint h1 = *(const uint*)(H + (size_t)s1 * 128 + c);
    uint h2 = *(const uint*)(H + (size_t)s2 * 128 + c);
    uint h3 = *(const uint*)(H + (size_t)s3 * 128 + c);
    uint h4 = *(const uint*)(H + (size_t)s4 * 128 + c);
    uint h5 = *(const uint*)(H + (size_t)s5 * 128 + c);
    uint h6 = *(const uint*)(H + (size_t)s6 * 128 + c);
    uint h7 = *(const uint*)(H + (size_t)s7 * 128 + c);
    a0 += bflo(h0) + bflo(h1) + bflo(h2) + bflo(h3);
    a1 += bfhi(h0) + bfhi(h1) + bfhi(h2) + bfhi(h3);
    a0 += bflo(h4) + bflo(h5) + bflo(h6) + bflo(h7);
    a1 += bfhi(h4) + bfhi(h5) + bfhi(h6) + bfhi(h7);
  }
  if (e + 4 <= end) {
    int s0 = csr[e], s1 = csr[e + 1], s2 = csr[e + 2], s3 = csr[e + 3];
    uint h0 = *(const uint*)(H + (size_t)s0 * 128 + c);
    uint h1 = *(const uint*)(H + (size_t)s1 * 128 + c);
    uint h2 = *(const uint*)(H + (size_t)s2 * 128 + c);
    uint h3 = *(const uint*)(H + (size_t)s3 * 128 + c);
    a0 += bflo(h0) + bflo(h1) + bflo(h2) + bflo(h3);
    a1 += bfhi(h0) + bfhi(h1) + bfhi(h2) + bfhi(h3);
    e += 4;
  }
  for (; e < end; e++) {
    int s = csr[e];
    uint h = *(const uint*)(H + (size_t)s * 128 + c);
    a0 += bflo(h);
    a1 += bfhi(h);
  }
  const float di = dinv[i];
  uint hs = *(const uint*)(H + (size_t)i * 128 + c);
  float r0 = di * (a0 + bflo(hs)) + b0;
  float r1 = di * (a1 + bfhi(hs)) + b1;
  r0 = fmaxf(r0, 0.f);
  r1 = fmaxf(r1, 0.f);
  *(uint*)(OUT + (size_t)i * 128 + c) = (uint)f2bf(r0) | ((uint)f2bf(r1) << 16);
}

// ---- Aggregation, C=64, no ReLU, fp32 out (+optional bf16 mirror) ---------

__global__ __launch_bounds__(256) void k_agg64(const __hip_bfloat16* __restrict__ H,
                                               const int* __restrict__ offs,
                                               const int* __restrict__ csr,
                                               const float* __restrict__ dinv,
                                               const float* __restrict__ b,
                                               float* __restrict__ OUT,
                                               __hip_bfloat16* __restrict__ MIR, int N) {
  const int lane = threadIdx.x & 63, wid = threadIdx.x >> 6;
  const int i = blockIdx.x * 4 + wid;
  if (i >= N) return;
  const int half = lane >> 5;
  const int c = (lane & 31) * 2;
  const float b0 = b[c], b1 = b[c + 1];
  const int beg = offs[i], end = offs[i + 1];
  float a0 = 0, a1 = 0;
  int e = beg + half;
  for (; e + 6 < end; e += 8) {
    int s0 = csr[e], s1 = csr[e + 2], s2 = csr[e + 4], s3 = csr[e + 6];
    uint h0 = *(const uint*)(H + (size_t)s0 * 64 + c);
    uint h1 = *(const uint*)(H + (size_t)s1 * 64 + c);
    uint h2 = *(const uint*)(H + (size_t)s2 * 64 + c);
    uint h3 = *(const uint*)(H + (size_t)s3 * 64 + c);
    a0 += bflo(h0) + bflo(h1) + bflo(h2) + bflo(h3);
    a1 += bfhi(h0) + bfhi(h1) + bfhi(h2) + bfhi(h3);
  }
  for (; e < end; e += 2) {
    int s = csr[e];
    uint h = *(const uint*)(H + (size_t)s * 64 + c);
    a0 += bflo(h);
    a1 += bfhi(h);
  }
  a0 += __shfl_xor(a0, 32);
  a1 += __shfl_xor(a1, 32);
  const float di = dinv[i];
  uint hs = *(const uint*)(H + (size_t)i * 64 + c);
  float r0 = di * (a0 + bflo(hs)) + b0;
  float r1 = di * (a1 + bfhi(hs)) + b1;
  if (lane < 32) {
    *(float2*)(OUT + (size_t)i * 64 + c) = make_float2(r0, r1);
    if (MIR) *(uint*)(MIR + (size_t)i * 64 + c) = (uint)f2bf(r0) | ((uint)f2bf(r1) << 16);
  }
}

// ---- Launch ---------------------------------------------------------------

extern "C" void kernel_launch(void* const* d_in, const int* in_sizes, int n_in,
                              void* d_out, int out_size, void* d_ws, size_t ws_size,
                              hipStream_t stream) {
  const float* x   = (const float*)d_in[0];
  const int*   ei  = (const int*)d_in[1];
  const float* W1n = (const float*)d_in[2];
  const float* b1n = (const float*)d_in[3];
  const float* W2n = (const float*)d_in[4];
  const float* b2n = (const float*)d_in[5];
  const float* W1e = (const float*)d_in[6];
  const float* b1e = (const float*)d_in[7];
  const float* W2e = (const float*)d_in[8];
  const float* b2e = (const float*)d_in[9];
  float* out = (float*)d_out;

  const int N = in_sizes[0] / 128;   // 100000
  const int E = in_sizes[1] / 2;     // 3200000
  const int C = (N + 31) >> 5;       // 3125 cells of 32 nodes
  const int P = (E + EPB - 1) / EPB; // 391 partitions
  const int* src = ei;
  const int* dst = ei + E;

  // workspace carve (256B aligned regions)
  char* p = (char*)d_ws;
  auto alloc = [&](size_t bytes) {
    void* q = (void*)p;
    p += (bytes + 255) & ~(size_t)255;
    return q;
  };
  int*   ctot  = (int*)alloc((size_t)C * 4);
  int*   boffs = (int*)alloc((size_t)(C + 1) * 4);
  int*   offs  = (int*)alloc((size_t)(N + 1) * 4);
  float* dinv  = (float*)alloc((size_t)N * 4);
  int*   csr   = (int*)alloc((size_t)E * 4);
  __hip_bfloat16* hbuf = (__hip_bfloat16*)alloc((size_t)N * 128 * 2);
  __hip_bfloat16* abuf = (__hip_bfloat16*)alloc((size_t)N * 128 * 2);
  // aliases (dead before their hosts are written):
  uint* psorted = (uint*)hbuf;            // P*EPB*4 = 12.8MB <= 25.6MB, dead before GEMM1
  int*  hist    = (int*)abuf;             // 4 x P*C*4 = 19.6MB <= 25.6MB, dead before k_cvt
  int*  pstart  = hist + (size_t)P * C;
  int*  histT   = pstart + (size_t)P * C;
  int*  pstartT = histT + (size_t)P * C;

  const int RB = (N + 15) >> 4;
  const int GEMM_GRID = RB < 1024 ? RB : 1024;

  // graph structure (shared by all 4 layers) — no atomics, no memset
  k_part<<<P, 256, 0, stream>>>(src, dst, E, C, psorted, hist, pstart);
  k_tr<<<dim3((P + 31) / 32, (C + 31) / 32), 256, 0, stream>>>(hist, histT, pstart, pstartT, P, C);
  k_ctot<<<(C * 64 + 255) / 256, 256, 0, stream>>>(histT, ctot, C, P);
  k_bscan<<<1, 1024, 0, stream>>>(ctot, boffs, C, E);
  k_binfill2<<<C, 256, 0, stream>>>(histT, pstartT, psorted, boffs, csr, offs, dinv, N, E, C, P);

  // x -> bf16 (abuf; hist arrays dead now)
  k_cvt<<<(N * 128 / 8 + 255) / 256, 256, 0, stream>>>(x, (uint*)abuf, N * 128 / 8);

  // layer 1
  k_mgemm<128, 128><<<GEMM_GRID, 256, 0, stream>>>(abuf, W1n, dinv, hbuf, N);
  k_agg128<<<(N + 3) / 4, 256, 0, stream>>>(hbuf, offs, csr, dinv, b1n, abuf, N);

  // layer 2: mu -> d_out[0:N*64), bf16 mirror -> abuf
  k_mgemm<128, 64><<<GEMM_GRID, 256, 0, stream>>>(abuf, W2n, dinv, hbuf, N);
  k_agg64<<<(N + 3) / 4, 256, 0, stream>>>(hbuf, offs, csr, dinv, b2n, out, abuf, N);

  // layer 3
  k_mgemm<64, 128><<<GEMM_GRID, 256, 0, stream>>>(abuf, W1e, dinv, hbuf, N);
  k_agg128<<<(N + 3) / 4, 256, 0, stream>>>(hbuf, offs, csr, dinv, b1e, abuf, N);

  // layer 4: logstd -> d_out[N*64 : 2*N*64)
  k_mgemm<128, 64><<<GEMM_GRID, 256, 0, stream>>>(abuf, W2e, dinv, hbuf, N);
  k_agg64<<<(N + 3) / 4, 256, 0, stream>>>(hbuf, offs, csr, dinv, b2e, out + (size_t)N * 64,
                                           (__hip_bfloat16*)nullptr, N);
}